// Round 8
// baseline (876.306 us; speedup 1.0000x reference)
//
#include <hip/hip_runtime.h>
#include <stdint.h>

typedef _Float16 f16;
typedef _Float16 f16x2 __attribute__((ext_vector_type(2)));
typedef _Float16 f16x8 __attribute__((ext_vector_type(8)));
typedef float f32x4 __attribute__((ext_vector_type(4)));

#define SEQ   512
#define BATCH 128
#define DIM   512
#define HID   256
#define G4    1024

typedef const __attribute__((address_space(1))) void* gas1p;
typedef __attribute__((address_space(3))) void* las3p;

__device__ __forceinline__ uint32_t pk2(float a, float b){
  return __builtin_bit_cast(uint32_t, __builtin_amdgcn_cvt_pkrtz(a, b));
}

__device__ __forceinline__ int sdot4(uint32_t a, uint32_t b, int c){
#if __has_builtin(__builtin_amdgcn_sdot4)
  return __builtin_amdgcn_sdot4(a, b, c, false);
#else
  int s = c;
  #pragma unroll
  for (int i = 0; i < 4; ++i){
    int ai = (int)(signed char)((a >> (8*i)) & 0xff);
    int bi = (int)(signed char)((b >> (8*i)) & 0xff);
    s += ai*bi;
  }
  return s;
#endif
}

__device__ __forceinline__ float sigm(float x){
  return __builtin_amdgcn_rcpf(1.0f + __expf(-x));
}
__device__ __forceinline__ float tanh_(float x){
  return 1.0f - 2.0f*__builtin_amdgcn_rcpf(__expf(2.0f*x) + 1.0f);
}

// ---------------- phase 0: fp32 -> f16 convert (vectorized, 8 elems/thread) ----
__global__ void __launch_bounds__(256) cvt_f16_kernel(const float* __restrict__ in,
                                                      f16* __restrict__ out, int n8){
  int i = blockIdx.x*blockDim.x + threadIdx.x;
  if (i >= n8) return;
  const float4* p = (const float4*)in;
  float4 a = p[2*i], b = p[2*i+1];
  uint4 r;
  r.x = pk2(a.x, a.y); r.y = pk2(a.z, a.w);
  r.z = pk2(b.x, b.y); r.w = pk2(b.z, b.w);
  ((uint4*)out)[i] = r;
}

// ---------------- phase 0b: quantize W_hh to i8 (scale 2048), per-thread layout -
// Word p (0..65535): lstm-thread t = p>>7, row r = (p>>5)&3, qq = p&31.
// Thread t: wave = t>>6, lane = t&63, unit j = wave*32 + (lane&31),
// k-half = (t>>5)&1. Gate row g = j + r*256; k-u32 kw = khalf*32 + qq.
__global__ void __launch_bounds__(256) prep_whh8(const float* __restrict__ Whh,
                                                 uint32_t* __restrict__ W8L){
  int p = blockIdx.x*256 + threadIdx.x;        // 0..65535
  int t  = p >> 7;
  int r  = (p >> 5) & 3;
  int qq = p & 31;
  int lane  = t & 63;
  int j     = (t >> 6)*32 + (lane & 31);
  int khalf = (lane >> 5) & 1;
  int g  = j + (r << 8);
  int kw = khalf*32 + qq;
  float4 v = *(const float4*)(Whh + g*HID + kw*4);
  int a = __float2int_rn(v.x*2048.f); a = a > 127 ? 127 : (a < -127 ? -127 : a);
  int b = __float2int_rn(v.y*2048.f); b = b > 127 ? 127 : (b < -127 ? -127 : b);
  int c = __float2int_rn(v.z*2048.f); c = c > 127 ? 127 : (c < -127 ? -127 : c);
  int d = __float2int_rn(v.w*2048.f); d = d > 127 ? 127 : (d < -127 ? -127 : d);
  W8L[p] = (uint32_t)(a & 0xff) | ((uint32_t)(b & 0xff) << 8) |
           ((uint32_t)(c & 0xff) << 16) | ((uint32_t)(d & 0xff) << 24);
}

// ---------------- phase 1: xg = x . W_ih^T + bias, f16 MFMA --------------------
// Epilogue writes QUAD layout: for gate col g, unit u=g&255, type tau=g>>8:
// C[m*1024 + u*4 + tau]  (so each unit's {i,f,g,o} are contiguous f16x4).
#define BM 128
#define BN 128
#define BK 64

__global__ void __launch_bounds__(256) gemm_xg_kernel(const f16* __restrict__ A,
                                                      const f16* __restrict__ Bm,
                                                      const float* __restrict__ bih,
                                                      const float* __restrict__ bhh,
                                                      f16* __restrict__ C){
  __shared__ __align__(16) f16 ldsA[BM*BK];
  __shared__ __align__(16) f16 ldsB[BN*BK];
  const int tid  = threadIdx.x;
  const int wave = tid >> 6;
  const int lane = tid & 63;
  const int bid  = blockIdx.x;
  const int nt   = bid & 7;
  const int mt   = bid >> 3;
  const long m0  = (long)mt * BM;
  const int n0   = nt * BN;
  const int wm   = wave >> 1, wn = wave & 1;
  const int lrow = lane >> 3;
  const int lk   = (lane & 7) * 8;

  f32x4 acc[4][4];
  #pragma unroll
  for (int i=0;i<4;++i)
    #pragma unroll
    for (int j=0;j<4;++j) acc[i][j] = (f32x4){0.f,0.f,0.f,0.f};

  auto ldsAq = (__attribute__((address_space(3))) char*)ldsA;
  auto ldsBq = (__attribute__((address_space(3))) char*)ldsB;

  for (int kt = 0; kt < DIM/BK; ++kt){
    const int k0 = kt*BK;
    __syncthreads();
    #pragma unroll
    for (int i = 0; i < 4; ++i){
      const int seg = wave*4 + i;
      const f16* ga = A  + (m0 + seg*8 + lrow)*DIM + (k0 + lk);
      const f16* gb = Bm + (long)(n0 + seg*8 + lrow)*DIM + (k0 + lk);
      __builtin_amdgcn_global_load_lds((gas1p)ga, (las3p)(ldsAq + seg*1024), 16, 0, 0);
      __builtin_amdgcn_global_load_lds((gas1p)gb, (las3p)(ldsBq + seg*1024), 16, 0, 0);
    }
    __syncthreads();
    #pragma unroll
    for (int kk = 0; kk < 2; ++kk){
      f16x8 af[4], bf[4];
      const int kb = kk*32 + (lane>>4)*8;
      #pragma unroll
      for (int mi=0; mi<4; ++mi){
        af[mi] = *(const f16x8*)(ldsA + (wm*64 + mi*16 + (lane&15))*BK + kb);
        bf[mi] = *(const f16x8*)(ldsB + (wn*64 + mi*16 + (lane&15))*BK + kb);
      }
      #pragma unroll
      for (int mi=0;mi<4;++mi)
        #pragma unroll
        for (int ni=0;ni<4;++ni)
          acc[mi][ni] = __builtin_amdgcn_mfma_f32_16x16x32_f16(af[mi], bf[ni], acc[mi][ni], 0,0,0);
    }
  }
  float bias[4];
  #pragma unroll
  for (int ni=0;ni<4;++ni){
    int col = n0 + wn*64 + ni*16 + (lane&15);
    bias[ni] = bih[col] + bhh[col];
  }
  #pragma unroll
  for (int mi=0;mi<4;++mi){
    #pragma unroll
    for (int ni=0;ni<4;++ni){
      int col = n0 + wn*64 + ni*16 + (lane&15);
      int cpos = (col & 255)*4 + (col >> 8);       // quad layout
      #pragma unroll
      for (int r=0;r<4;++r){
        long row = m0 + wm*64 + mi*16 + (lane>>4)*4 + r;
        C[row*G4 + cpos] = (f16)(acc[mi][ni][r] + bias[ni]);
      }
    }
  }
}

// ---------------- phase 2: sequential LSTM (i8 dot4) + fused FC head -----------
// 128 blocks x 512 threads (8 waves = 2/SIMD, 1 block/CU). Lanes l and l^32 of
// wave w share unit j = w*32 + (l&31); each holds one k-half (128 k) of all 4
// gate rows as 128 u32 i8-quads PINNED IN AGPRS (explicit v_accvgpr_write).
// AGPR-class values can't be rematerialized from memory -> guaranteed resident
// (AGPR 128 + VGPR ~90 fits the 256-reg budget at 2 waves/EU). Each use costs
// one volatile v_accvgpr_read (volatile stops CSE from hoisting 128 temps).
// Partials combined via __shfl_xor(32); ONE barrier per step; h: i8[2][256]
// LDS double buffer (2-address broadcast reads = conflict-free).
__global__ void
__attribute__((amdgpu_flat_work_group_size(512, 512), amdgpu_waves_per_eu(2, 2)))
lstm8_kernel(const f16* __restrict__ xq,
             const uint32_t* __restrict__ W8L,
             const float* __restrict__ fcw,
             const float* __restrict__ fcb,
             float* __restrict__ out){
  __shared__ __align__(16) uint8_t h8[2][256];
  __shared__ float red[256];
  const int t = threadIdx.x;
  const int b = blockIdx.x;
  const int lane  = t & 63;
  const int j     = (t >> 6)*32 + (lane & 31);
  const int khalf = lane >> 5;
  const float invS = 1.0f / (2048.0f * 127.0f);

  // ---- load 128 weight words straight into AGPRs (4 at a time, low VGPR peak)
  uint32_t wa[128];
  {
    const uint4* wp = (const uint4*)(W8L + (size_t)t*128);
    #pragma unroll
    for (int q8 = 0; q8 < 32; ++q8){
      uint4 u = wp[q8];
      asm volatile("v_accvgpr_write_b32 %0, %1" : "=a"(wa[4*q8+0]) : "v"(u.x));
      asm volatile("v_accvgpr_write_b32 %0, %1" : "=a"(wa[4*q8+1]) : "v"(u.y));
      asm volatile("v_accvgpr_write_b32 %0, %1" : "=a"(wa[4*q8+2]) : "v"(u.z));
      asm volatile("v_accvgpr_write_b32 %0, %1" : "=a"(wa[4*q8+3]) : "v"(u.w));
    }
  }

  if (t < 128) ((uint32_t*)h8)[t] = 0;         // zero both h buffers

  const f16* xrow = xq + (long)b * SEQ * G4;
  ushort4 xv = *(const ushort4*)(xrow + j*4);  // step-0 gate quad {i,f,g,o}
  float c = 0.f, hlast = 0.f;
  __syncthreads();

  for (int ts = 0; ts < SEQ; ++ts){
    // consume current xv; issue next-step prefetch IMMEDIATELY (full-step cover)
    ushort4 xc = xv;
    if (ts + 1 < SEQ) xv = *(const ushort4*)(xrow + (ts+1)*G4 + j*4);

    const uint4* hq = (const uint4*)&h8[ts & 1][khalf*128];
    uint4 hv[8];
    #pragma unroll
    for (int q = 0; q < 8; ++q) hv[q] = hq[q];  // 2-addr broadcast reads

    int acc[4] = {0, 0, 0, 0};
    #pragma unroll
    for (int q = 0; q < 8; ++q){                // q-major: 4 indep chains (rows)
      #pragma unroll
      for (int r = 0; r < 4; ++r){
        uint32_t t0, t1, t2, t3;
        asm volatile("v_accvgpr_read_b32 %0, %1" : "=v"(t0) : "a"(wa[r*32+4*q+0]));
        asm volatile("v_accvgpr_read_b32 %0, %1" : "=v"(t1) : "a"(wa[r*32+4*q+1]));
        asm volatile("v_accvgpr_read_b32 %0, %1" : "=v"(t2) : "a"(wa[r*32+4*q+2]));
        asm volatile("v_accvgpr_read_b32 %0, %1" : "=v"(t3) : "a"(wa[r*32+4*q+3]));
        acc[r] = sdot4(t0, hv[q].x, acc[r]);
        acc[r] = sdot4(t1, hv[q].y, acc[r]);
        acc[r] = sdot4(t2, hv[q].z, acc[r]);
        acc[r] = sdot4(t3, hv[q].w, acc[r]);
      }
    }
    // combine the two k-halves within the wave (lanes l <-> l^32), no barrier
    #pragma unroll
    for (int r = 0; r < 4; ++r) acc[r] += __shfl_xor(acc[r], 32);

    // activations (both halves compute identically; lane-duplication is free)
    f16 xi  = __builtin_bit_cast(f16, xc.x), xf = __builtin_bit_cast(f16, xc.y);
    f16 xg_ = __builtin_bit_cast(f16, xc.z), xo = __builtin_bit_cast(f16, xc.w);
    float gi = (float)xi  + (float)acc[0]*invS;
    float gf = (float)xf  + (float)acc[1]*invS;
    float gg = (float)xg_ + (float)acc[2]*invS;
    float go = (float)xo  + (float)acc[3]*invS;
    float iv = sigm(gi), fv = sigm(gf), gv = tanh_(gg), ov = sigm(go);
    c     = fv*c + iv*gv;
    hlast = ov * tanh_(c);
    int hq8 = __float2int_rn(hlast * 127.f);
    if (khalf == 0) h8[(ts+1) & 1][j] = (uint8_t)(hq8 & 0xff);
    __syncthreads();                            // ONE barrier per step
  }

  // ---- fused FC head
  if (khalf == 0) red[j] = hlast * fcw[j];
  __syncthreads();
  if (t < 64){
    float s = red[t] + red[t+64] + red[t+128] + red[t+192];
    #pragma unroll
    for (int off = 32; off; off >>= 1) s += __shfl_down(s, off);
    if (t == 0) out[b] = s + fcb[0];
  }
}

extern "C" void kernel_launch(void* const* d_in, const int* in_sizes, int n_in,
                              void* d_out, int out_size, void* d_ws, size_t ws_size,
                              hipStream_t stream) {
  const float* x   = (const float*)d_in[0];
  const float* Wih = (const float*)d_in[1];
  const float* Whh = (const float*)d_in[2];
  const float* bih = (const float*)d_in[3];
  const float* bhh = (const float*)d_in[4];
  const float* fcw = (const float*)d_in[5];
  const float* fcb = (const float*)d_in[6];
  float* out = (float*)d_out;

  char* ws = (char*)d_ws;
  f16*      xh  = (f16*)ws;                                //  67,108,864 B
  f16*      Wh  = (f16*)(ws + 67108864);                   //   1,048,576 B
  f16*      xq  = (f16*)(ws + 68157440);                   // 134,217,728 B
  uint32_t* W8L = (uint32_t*)(ws + 202375168);             //     262,144 B

  cvt_f16_kernel<<<16384, 256, 0, stream>>>(x,   xh, 33554432/8);
  cvt_f16_kernel<<<256,   256, 0, stream>>>(Wih, Wh, 524288/8);
  prep_whh8<<<256, 256, 0, stream>>>(Whh, W8L);
  gemm_xg_kernel<<<4096, 256, 0, stream>>>(xh, Wh, bih, bhh, xq);
  lstm8_kernel<<<BATCH, 512, 0, stream>>>(xq, W8L, fcw, fcb, out);
}

// Round 9
// 671.511 us; speedup vs baseline: 1.3050x; 1.3050x over previous
//
#include <hip/hip_runtime.h>
#include <stdint.h>

typedef _Float16 f16;
typedef _Float16 f16x2 __attribute__((ext_vector_type(2)));
typedef _Float16 f16x8 __attribute__((ext_vector_type(8)));
typedef float f32x4 __attribute__((ext_vector_type(4)));

#define SEQ   512
#define BATCH 128
#define DIM   512
#define HID   256
#define G4    1024

typedef const __attribute__((address_space(1))) void* gas1p;
typedef __attribute__((address_space(3))) void* las3p;

__device__ __forceinline__ uint32_t pk2(float a, float b){
  return __builtin_bit_cast(uint32_t, __builtin_amdgcn_cvt_pkrtz(a, b));
}

__device__ __forceinline__ int sdot4(uint32_t a, uint32_t b, int c){
#if __has_builtin(__builtin_amdgcn_sdot4)
  return __builtin_amdgcn_sdot4(a, b, c, false);
#else
  int s = c;
  #pragma unroll
  for (int i = 0; i < 4; ++i){
    int ai = (int)(signed char)((a >> (8*i)) & 0xff);
    int bi = (int)(signed char)((b >> (8*i)) & 0xff);
    s += ai*bi;
  }
  return s;
#endif
}

__device__ __forceinline__ float sigm(float x){
  return __builtin_amdgcn_rcpf(1.0f + __expf(-x));
}
__device__ __forceinline__ float tanh_(float x){
  return 1.0f - 2.0f*__builtin_amdgcn_rcpf(__expf(2.0f*x) + 1.0f);
}

__device__ __forceinline__ int q8(float v){
  int a = __float2int_rn(v * 2048.f);
  return a > 127 ? 127 : (a < -127 ? -127 : a);
}

// ---------------- phase 0: fp32 -> f16 convert (vectorized, 8 elems/thread) ----
__global__ void __launch_bounds__(256) cvt_f16_kernel(const float* __restrict__ in,
                                                      f16* __restrict__ out, int n8){
  int i = blockIdx.x*blockDim.x + threadIdx.x;
  if (i >= n8) return;
  const float4* p = (const float4*)in;
  float4 a = p[2*i], b = p[2*i+1];
  uint4 r;
  r.x = pk2(a.x, a.y); r.y = pk2(a.z, a.w);
  r.z = pk2(b.x, b.y); r.w = pk2(b.z, b.w);
  ((uint4*)out)[i] = r;
}

// ---------------- phase 0b: quantize W_hh to i8 (scale 2048), two layouts ------
// Layout R (words 0..49151): rows i,f,g in per-thread blocks.
//   p = t*192 + r*64 + kw   (t=unit 0..255, r=0..2, kw=word 0..63)
//   packs Whh[t + r*256][4kw .. 4kw+4)
// Layout O (words 0..16383, separate buffer): row o, LDS-interleaved.
//   pB = q4*1024 + t*4 + w  (q4=0..15, w=0..3, kw = 4*q4+w)
//   packs Whh[t + 768][4kw .. 4kw+4)
__global__ void __launch_bounds__(256) prep_whh8(const float* __restrict__ Whh,
                                                 uint32_t* __restrict__ W8R,
                                                 uint32_t* __restrict__ W8O){
  int p = blockIdx.x*256 + threadIdx.x;        // 0..65535
  int g, kw;
  uint32_t* dst;
  int idx;
  if (p < 49152){
    int t = p / 192, rem = p % 192;
    int r = rem >> 6;
    kw = rem & 63;
    g = t + (r << 8);
    dst = W8R; idx = p;
  } else {
    int pB = p - 49152;
    int q4 = pB >> 10, t = (pB >> 2) & 255, w = pB & 3;
    kw = q4*4 + w;
    g = t + 768;
    dst = W8O; idx = pB;
  }
  float4 v = *(const float4*)(Whh + g*HID + kw*4);
  int a = q8(v.x), b = q8(v.y), c = q8(v.z), d = q8(v.w);
  dst[idx] = (uint32_t)(a & 0xff) | ((uint32_t)(b & 0xff) << 8) |
             ((uint32_t)(c & 0xff) << 16) | ((uint32_t)(d & 0xff) << 24);
}

// ---------------- phase 1: xg = x . W_ih^T + bias, f16 MFMA --------------------
// Epilogue writes QUAD layout: for gate col g, unit u=g&255, type tau=g>>8:
// C[m*1024 + u*4 + tau]  (so each unit's {i,f,g,o} are contiguous f16x4).
#define BM 128
#define BN 128
#define BK 64

__global__ void __launch_bounds__(256) gemm_xg_kernel(const f16* __restrict__ A,
                                                      const f16* __restrict__ Bm,
                                                      const float* __restrict__ bih,
                                                      const float* __restrict__ bhh,
                                                      f16* __restrict__ C){
  __shared__ __align__(16) f16 ldsA[BM*BK];
  __shared__ __align__(16) f16 ldsB[BN*BK];
  const int tid  = threadIdx.x;
  const int wave = tid >> 6;
  const int lane = tid & 63;
  const int bid  = blockIdx.x;
  const int nt   = bid & 7;
  const int mt   = bid >> 3;
  const long m0  = (long)mt * BM;
  const int n0   = nt * BN;
  const int wm   = wave >> 1, wn = wave & 1;
  const int lrow = lane >> 3;
  const int lk   = (lane & 7) * 8;

  f32x4 acc[4][4];
  #pragma unroll
  for (int i=0;i<4;++i)
    #pragma unroll
    for (int j=0;j<4;++j) acc[i][j] = (f32x4){0.f,0.f,0.f,0.f};

  auto ldsAq = (__attribute__((address_space(3))) char*)ldsA;
  auto ldsBq = (__attribute__((address_space(3))) char*)ldsB;

  for (int kt = 0; kt < DIM/BK; ++kt){
    const int k0 = kt*BK;
    __syncthreads();
    #pragma unroll
    for (int i = 0; i < 4; ++i){
      const int seg = wave*4 + i;
      const f16* ga = A  + (m0 + seg*8 + lrow)*DIM + (k0 + lk);
      const f16* gb = Bm + (long)(n0 + seg*8 + lrow)*DIM + (k0 + lk);
      __builtin_amdgcn_global_load_lds((gas1p)ga, (las3p)(ldsAq + seg*1024), 16, 0, 0);
      __builtin_amdgcn_global_load_lds((gas1p)gb, (las3p)(ldsBq + seg*1024), 16, 0, 0);
    }
    __syncthreads();
    #pragma unroll
    for (int kk = 0; kk < 2; ++kk){
      f16x8 af[4], bf[4];
      const int kb = kk*32 + (lane>>4)*8;
      #pragma unroll
      for (int mi=0; mi<4; ++mi){
        af[mi] = *(const f16x8*)(ldsA + (wm*64 + mi*16 + (lane&15))*BK + kb);
        bf[mi] = *(const f16x8*)(ldsB + (wn*64 + mi*16 + (lane&15))*BK + kb);
      }
      #pragma unroll
      for (int mi=0;mi<4;++mi)
        #pragma unroll
        for (int ni=0;ni<4;++ni)
          acc[mi][ni] = __builtin_amdgcn_mfma_f32_16x16x32_f16(af[mi], bf[ni], acc[mi][ni], 0,0,0);
    }
  }
  float bias[4];
  #pragma unroll
  for (int ni=0;ni<4;++ni){
    int col = n0 + wn*64 + ni*16 + (lane&15);
    bias[ni] = bih[col] + bhh[col];
  }
  #pragma unroll
  for (int mi=0;mi<4;++mi){
    #pragma unroll
    for (int ni=0;ni<4;++ni){
      int col = n0 + wn*64 + ni*16 + (lane&15);
      int cpos = (col & 255)*4 + (col >> 8);       // quad layout
      #pragma unroll
      for (int r=0;r<4;++r){
        long row = m0 + wm*64 + mi*16 + (lane>>4)*4 + r;
        C[row*G4 + cpos] = (f16)(acc[mi][ni][r] + bias[ni]);
      }
    }
  }
}

// ---------------- phase 2: sequential LSTM (i8 dot4) + fused FC head -----------
// 128 blocks x 256 threads (4 waves = 1 wave/SIMD — the ONLY shape where RA
// demonstrably allocates >128 VGPRs (r4: 240)). Thread t owns LSTM unit t:
// all 4 gate rows, full k. Rows i,f,g = 192 u32 i8-quads in VGPRs (demand
// ~224 <= 240); row o = 64 KB in LDS, read as contiguous-per-wave b128.
// h: i8[2][256] LDS double buffer, wave-uniform broadcast quads. No partial
// exchange, no shfl; ONE barrier per step.
__global__ void
__attribute__((amdgpu_flat_work_group_size(256, 256), amdgpu_waves_per_eu(1, 1)))
lstm8_kernel(const f16* __restrict__ xq,
             const uint32_t* __restrict__ W8R,
             const uint4* __restrict__ W8O,
             const float* __restrict__ fcw,
             const float* __restrict__ fcb,
             float* __restrict__ out){
  extern __shared__ __align__(16) char smem[];
  uint4*   WoL = (uint4*)smem;                 // 4096 uint4 = 64 KiB (o-row)
  uint8_t* h8  = (uint8_t*)(smem + 65536);     // [2][256] i8 h double buffer
  float*   red = (float*)(smem + 66048);       // 256 f32 reduce
  const int t = threadIdx.x;
  const int b = blockIdx.x;
  const float invS = 1.0f / (2048.0f * 127.0f);

  // cooperative LDS fill of o-row weights (coalesced, one-time)
  #pragma unroll
  for (int i = 0; i < 16; ++i) WoL[i*256 + t] = W8O[i*256 + t];

  // register weights: rows i,f,g — 48 uint4 = 192 u32
  uint4 w4[48];
  {
    const uint4* wp = (const uint4*)(W8R + (size_t)t*192);
    #pragma unroll
    for (int i = 0; i < 48; ++i) w4[i] = wp[i];
  }

  if (t < 128) ((uint32_t*)h8)[t] = 0;         // zero both h buffers
  const f16* xrow = xq + (long)b * SEQ * G4;
  ushort4 xv = *(const ushort4*)(xrow + t*4);  // step-0 gate quad {i,f,g,o}
  float c = 0.f, hlast = 0.f;
  __syncthreads();

  for (int ts = 0; ts < SEQ; ++ts){
    ushort4 xc = xv;
    if (ts + 1 < SEQ) xv = *(const ushort4*)(xrow + (ts+1)*G4 + t*4);

    const uint4* hq = (const uint4*)&h8[(ts & 1)*256];
    int a0 = 0, a1 = 0, a2 = 0, a3 = 0;
    #pragma unroll
    for (int q4 = 0; q4 < 16; ++q4){
      uint4 hv = hq[q4];                       // wave-uniform broadcast read
      uint4 wo = WoL[q4*256 + t];              // contiguous-per-wave b128
      uint4 wi = w4[q4], wf = w4[16 + q4], wg = w4[32 + q4];
      a0 = sdot4(wi.x, hv.x, a0); a0 = sdot4(wi.y, hv.y, a0);
      a0 = sdot4(wi.z, hv.z, a0); a0 = sdot4(wi.w, hv.w, a0);
      a1 = sdot4(wf.x, hv.x, a1); a1 = sdot4(wf.y, hv.y, a1);
      a1 = sdot4(wf.z, hv.z, a1); a1 = sdot4(wf.w, hv.w, a1);
      a2 = sdot4(wg.x, hv.x, a2); a2 = sdot4(wg.y, hv.y, a2);
      a2 = sdot4(wg.z, hv.z, a2); a2 = sdot4(wg.w, hv.w, a2);
      a3 = sdot4(wo.x, hv.x, a3); a3 = sdot4(wo.y, hv.y, a3);
      a3 = sdot4(wo.z, hv.z, a3); a3 = sdot4(wo.w, hv.w, a3);
    }

    f16 xi  = __builtin_bit_cast(f16, xc.x), xf = __builtin_bit_cast(f16, xc.y);
    f16 xg_ = __builtin_bit_cast(f16, xc.z), xo = __builtin_bit_cast(f16, xc.w);
    float gi = (float)xi  + (float)a0*invS;
    float gf = (float)xf  + (float)a1*invS;
    float gg = (float)xg_ + (float)a2*invS;
    float go = (float)xo  + (float)a3*invS;
    float iv = sigm(gi), fv = sigm(gf), gv = tanh_(gg), ov = sigm(go);
    c     = fv*c + iv*gv;
    hlast = ov * tanh_(c);
    int hv8 = __float2int_rn(hlast * 127.f);
    h8[((ts+1) & 1)*256 + t] = (uint8_t)(hv8 & 0xff);
    __syncthreads();                           // ONE barrier per step
  }

  // ---- fused FC head: out[b] = h . fc_w + fc_b
  red[t] = hlast * fcw[t];
  __syncthreads();
  if (t < 64){
    float s = red[t] + red[t+64] + red[t+128] + red[t+192];
    #pragma unroll
    for (int off = 32; off; off >>= 1) s += __shfl_down(s, off);
    if (t == 0) out[b] = s + fcb[0];
  }
}

extern "C" void kernel_launch(void* const* d_in, const int* in_sizes, int n_in,
                              void* d_out, int out_size, void* d_ws, size_t ws_size,
                              hipStream_t stream) {
  const float* x   = (const float*)d_in[0];
  const float* Wih = (const float*)d_in[1];
  const float* Whh = (const float*)d_in[2];
  const float* bih = (const float*)d_in[3];
  const float* bhh = (const float*)d_in[4];
  const float* fcw = (const float*)d_in[5];
  const float* fcb = (const float*)d_in[6];
  float* out = (float*)d_out;

  char* ws = (char*)d_ws;
  f16*      xh  = (f16*)ws;                                //  67,108,864 B
  f16*      Wh  = (f16*)(ws + 67108864);                   //   1,048,576 B
  f16*      xq  = (f16*)(ws + 68157440);                   // 134,217,728 B
  uint32_t* W8R = (uint32_t*)(ws + 202375168);             //     196,608 B
  uint32_t* W8O = (uint32_t*)(ws + 202571776);             //      65,536 B

  cvt_f16_kernel<<<16384, 256, 0, stream>>>(x,   xh, 33554432/8);
  cvt_f16_kernel<<<256,   256, 0, stream>>>(Wih, Wh, 524288/8);
  prep_whh8<<<256, 256, 0, stream>>>(Whh, W8R, W8O);
  gemm_xg_kernel<<<4096, 256, 0, stream>>>(xh, Wh, bih, bhh, xq);
  (void)hipFuncSetAttribute(reinterpret_cast<const void*>(lstm8_kernel),
                            hipFuncAttributeMaxDynamicSharedMemorySize, 67072);
  lstm8_kernel<<<BATCH, 256, 67072, stream>>>(xq, W8R, (const uint4*)W8O,
                                              fcw, fcb, out);
}

// Round 10
// 670.037 us; speedup vs baseline: 1.3078x; 1.0022x over previous
//
#include <hip/hip_runtime.h>
#include <stdint.h>

typedef _Float16 f16;
typedef _Float16 f16x2 __attribute__((ext_vector_type(2)));
typedef _Float16 f16x8 __attribute__((ext_vector_type(8)));
typedef float f32x4 __attribute__((ext_vector_type(4)));

#define SEQ   512
#define BATCH 128
#define DIM   512
#define HID   256
#define G4    1024

typedef const __attribute__((address_space(1))) void* gas1p;
typedef __attribute__((address_space(3))) void* las3p;

__device__ __forceinline__ uint32_t pk2(float a, float b){
  return __builtin_bit_cast(uint32_t, __builtin_amdgcn_cvt_pkrtz(a, b));
}

__device__ __forceinline__ int sdot4(uint32_t a, uint32_t b, int c){
#if __has_builtin(__builtin_amdgcn_sdot4)
  return __builtin_amdgcn_sdot4(a, b, c, false);
#else
  int s = c;
  #pragma unroll
  for (int i = 0; i < 4; ++i){
    int ai = (int)(signed char)((a >> (8*i)) & 0xff);
    int bi = (int)(signed char)((b >> (8*i)) & 0xff);
    s += ai*bi;
  }
  return s;
#endif
}

__device__ __forceinline__ float sigm(float x){
  return __builtin_amdgcn_rcpf(1.0f + __expf(-x));
}
__device__ __forceinline__ float tanh_(float x){
  return 1.0f - 2.0f*__builtin_amdgcn_rcpf(__expf(2.0f*x) + 1.0f);
}

__device__ __forceinline__ int q8(float v){
  int a = __float2int_rn(v * 2048.f);
  return a > 127 ? 127 : (a < -127 ? -127 : a);
}

// ---------------- phase 0: fp32 -> f16 convert (vectorized, 8 elems/thread) ----
__global__ void __launch_bounds__(256) cvt_f16_kernel(const float* __restrict__ in,
                                                      f16* __restrict__ out, int n8){
  int i = blockIdx.x*blockDim.x + threadIdx.x;
  if (i >= n8) return;
  const float4* p = (const float4*)in;
  float4 a = p[2*i], b = p[2*i+1];
  uint4 r;
  r.x = pk2(a.x, a.y); r.y = pk2(a.z, a.w);
  r.z = pk2(b.x, b.y); r.w = pk2(b.z, b.w);
  ((uint4*)out)[i] = r;
}

// ---------------- phase 0b: quantize W_hh to i8 (scale 2048), two layouts ------
// Layout R (words 0..49151): rows i,f,g in per-thread blocks.
//   p = t*192 + r*64 + kw   (t=unit 0..255, r=0..2, kw=word 0..63)
//   packs Whh[t + r*256][4kw .. 4kw+4)
// Layout O (words 0..16383, separate buffer): row o, LDS-interleaved.
//   pB = q4*1024 + t*4 + w  (q4=0..15, w=0..3, kw = 4*q4+w)
//   packs Whh[t + 768][4kw .. 4kw+4)
__global__ void __launch_bounds__(256) prep_whh8(const float* __restrict__ Whh,
                                                 uint32_t* __restrict__ W8R,
                                                 uint32_t* __restrict__ W8O){
  int p = blockIdx.x*256 + threadIdx.x;        // 0..65535
  int g, kw;
  uint32_t* dst;
  int idx;
  if (p < 49152){
    int t = p / 192, rem = p % 192;
    int r = rem >> 6;
    kw = rem & 63;
    g = t + (r << 8);
    dst = W8R; idx = p;
  } else {
    int pB = p - 49152;
    int q4 = pB >> 10, t = (pB >> 2) & 255, w = pB & 3;
    kw = q4*4 + w;
    g = t + 768;
    dst = W8O; idx = pB;
  }
  float4 v = *(const float4*)(Whh + g*HID + kw*4);
  int a = q8(v.x), b = q8(v.y), c = q8(v.z), d = q8(v.w);
  dst[idx] = (uint32_t)(a & 0xff) | ((uint32_t)(b & 0xff) << 8) |
             ((uint32_t)(c & 0xff) << 16) | ((uint32_t)(d & 0xff) << 24);
}

// ---------------- phase 1: xg = x . W_ih^T + bias, f16 MFMA --------------------
// Epilogue writes QUAD layout: for gate col g, unit u=g&255, type tau=g>>8:
// C[m*1024 + u*4 + tau]  (so each unit's {i,f,g,o} are contiguous f16x4).
#define BM 128
#define BN 128
#define BK 64

__global__ void __launch_bounds__(256) gemm_xg_kernel(const f16* __restrict__ A,
                                                      const f16* __restrict__ Bm,
                                                      const float* __restrict__ bih,
                                                      const float* __restrict__ bhh,
                                                      f16* __restrict__ C){
  __shared__ __align__(16) f16 ldsA[BM*BK];
  __shared__ __align__(16) f16 ldsB[BN*BK];
  const int tid  = threadIdx.x;
  const int wave = tid >> 6;
  const int lane = tid & 63;
  const int bid  = blockIdx.x;
  const int nt   = bid & 7;
  const int mt   = bid >> 3;
  const long m0  = (long)mt * BM;
  const int n0   = nt * BN;
  const int wm   = wave >> 1, wn = wave & 1;
  const int lrow = lane >> 3;
  const int lk   = (lane & 7) * 8;

  f32x4 acc[4][4];
  #pragma unroll
  for (int i=0;i<4;++i)
    #pragma unroll
    for (int j=0;j<4;++j) acc[i][j] = (f32x4){0.f,0.f,0.f,0.f};

  auto ldsAq = (__attribute__((address_space(3))) char*)ldsA;
  auto ldsBq = (__attribute__((address_space(3))) char*)ldsB;

  for (int kt = 0; kt < DIM/BK; ++kt){
    const int k0 = kt*BK;
    __syncthreads();
    #pragma unroll
    for (int i = 0; i < 4; ++i){
      const int seg = wave*4 + i;
      const f16* ga = A  + (m0 + seg*8 + lrow)*DIM + (k0 + lk);
      const f16* gb = Bm + (long)(n0 + seg*8 + lrow)*DIM + (k0 + lk);
      __builtin_amdgcn_global_load_lds((gas1p)ga, (las3p)(ldsAq + seg*1024), 16, 0, 0);
      __builtin_amdgcn_global_load_lds((gas1p)gb, (las3p)(ldsBq + seg*1024), 16, 0, 0);
    }
    __syncthreads();
    #pragma unroll
    for (int kk = 0; kk < 2; ++kk){
      f16x8 af[4], bf[4];
      const int kb = kk*32 + (lane>>4)*8;
      #pragma unroll
      for (int mi=0; mi<4; ++mi){
        af[mi] = *(const f16x8*)(ldsA + (wm*64 + mi*16 + (lane&15))*BK + kb);
        bf[mi] = *(const f16x8*)(ldsB + (wn*64 + mi*16 + (lane&15))*BK + kb);
      }
      #pragma unroll
      for (int mi=0;mi<4;++mi)
        #pragma unroll
        for (int ni=0;ni<4;++ni)
          acc[mi][ni] = __builtin_amdgcn_mfma_f32_16x16x32_f16(af[mi], bf[ni], acc[mi][ni], 0,0,0);
    }
  }
  float bias[4];
  #pragma unroll
  for (int ni=0;ni<4;++ni){
    int col = n0 + wn*64 + ni*16 + (lane&15);
    bias[ni] = bih[col] + bhh[col];
  }
  #pragma unroll
  for (int mi=0;mi<4;++mi){
    #pragma unroll
    for (int ni=0;ni<4;++ni){
      int col = n0 + wn*64 + ni*16 + (lane&15);
      int cpos = (col & 255)*4 + (col >> 8);       // quad layout
      #pragma unroll
      for (int r=0;r<4;++r){
        long row = m0 + wm*64 + mi*16 + (lane>>4)*4 + r;
        C[row*G4 + cpos] = (f16)(acc[mi][ni][r] + bias[ni]);
      }
    }
  }
}

// ---------------- phase 2: sequential LSTM (i8 dot4) + fused FC head -----------
// 128 blocks x 256 threads (4 waves = 1 wave/SIMD). Thread t owns LSTM unit t:
// all 4 gate rows, full k. Rows i,f,g = 192 u32 i8-quads in VGPRs; row o =
// 64 KB in LDS (contiguous-per-wave b128 stream). h: i8[2][256] LDS double
// buffer, wave-uniform broadcast quads. ONE barrier per step.
// ATTRIBUTES: single-arg __launch_bounds__(256) + amdgpu_waves_per_eu(1,1) is
// the ONLY combo measured to unlock >128 VGPRs (r4: 240 granted). Register
// demand here ~230 <= 240 -> weights actually resident this time.
__global__ void __launch_bounds__(256)
__attribute__((amdgpu_waves_per_eu(1, 1)))
lstm8_kernel(const f16* __restrict__ xq,
             const uint32_t* __restrict__ W8R,
             const uint4* __restrict__ W8O,
             const float* __restrict__ fcw,
             const float* __restrict__ fcb,
             float* __restrict__ out){
  extern __shared__ __align__(16) char smem[];
  uint4*   WoL = (uint4*)smem;                 // 4096 uint4 = 64 KiB (o-row)
  uint8_t* h8  = (uint8_t*)(smem + 65536);     // [2][256] i8 h double buffer
  float*   red = (float*)(smem + 66048);       // 256 f32 reduce
  const int t = threadIdx.x;
  const int b = blockIdx.x;
  const float invS = 1.0f / (2048.0f * 127.0f);

  // cooperative LDS fill of o-row weights (coalesced, one-time)
  #pragma unroll
  for (int i = 0; i < 16; ++i) WoL[i*256 + t] = W8O[i*256 + t];

  // register weights: rows i,f,g — 48 uint4 = 192 u32
  uint4 w4[48];
  {
    const uint4* wp = (const uint4*)(W8R + (size_t)t*192);
    #pragma unroll
    for (int i = 0; i < 48; ++i) w4[i] = wp[i];
  }

  if (t < 128) ((uint32_t*)h8)[t] = 0;         // zero both h buffers
  const f16* xrow = xq + (long)b * SEQ * G4;
  ushort4 xv = *(const ushort4*)(xrow + t*4);  // step-0 gate quad {i,f,g,o}
  float c = 0.f, hlast = 0.f;
  __syncthreads();

  for (int ts = 0; ts < SEQ; ++ts){
    ushort4 xc = xv;
    if (ts + 1 < SEQ) xv = *(const ushort4*)(xrow + (ts+1)*G4 + t*4);

    const uint4* hq = (const uint4*)&h8[(ts & 1)*256];
    int a0 = 0, a1 = 0, a2 = 0, a3 = 0;
    #pragma unroll
    for (int q4 = 0; q4 < 16; ++q4){
      uint4 hv = hq[q4];                       // wave-uniform broadcast read
      uint4 wo = WoL[q4*256 + t];              // contiguous-per-wave b128
      uint4 wi = w4[q4], wf = w4[16 + q4], wg = w4[32 + q4];
      a0 = sdot4(wi.x, hv.x, a0); a0 = sdot4(wi.y, hv.y, a0);
      a0 = sdot4(wi.z, hv.z, a0); a0 = sdot4(wi.w, hv.w, a0);
      a1 = sdot4(wf.x, hv.x, a1); a1 = sdot4(wf.y, hv.y, a1);
      a1 = sdot4(wf.z, hv.z, a1); a1 = sdot4(wf.w, hv.w, a1);
      a2 = sdot4(wg.x, hv.x, a2); a2 = sdot4(wg.y, hv.y, a2);
      a2 = sdot4(wg.z, hv.z, a2); a2 = sdot4(wg.w, hv.w, a2);
      a3 = sdot4(wo.x, hv.x, a3); a3 = sdot4(wo.y, hv.y, a3);
      a3 = sdot4(wo.z, hv.z, a3); a3 = sdot4(wo.w, hv.w, a3);
    }

    f16 xi  = __builtin_bit_cast(f16, xc.x), xf = __builtin_bit_cast(f16, xc.y);
    f16 xg_ = __builtin_bit_cast(f16, xc.z), xo = __builtin_bit_cast(f16, xc.w);
    float gi = (float)xi  + (float)a0*invS;
    float gf = (float)xf  + (float)a1*invS;
    float gg = (float)xg_ + (float)a2*invS;
    float go = (float)xo  + (float)a3*invS;
    float iv = sigm(gi), fv = sigm(gf), gv = tanh_(gg), ov = sigm(go);
    c     = fv*c + iv*gv;
    hlast = ov * tanh_(c);
    int hv8 = __float2int_rn(hlast * 127.f);
    h8[((ts+1) & 1)*256 + t] = (uint8_t)(hv8 & 0xff);
    __syncthreads();                           // ONE barrier per step
  }

  // ---- fused FC head: out[b] = h . fc_w + fc_b
  red[t] = hlast * fcw[t];
  __syncthreads();
  if (t < 64){
    float s = red[t] + red[t+64] + red[t+128] + red[t+192];
    #pragma unroll
    for (int off = 32; off; off >>= 1) s += __shfl_down(s, off);
    if (t == 0) out[b] = s + fcb[0];
  }
}

extern "C" void kernel_launch(void* const* d_in, const int* in_sizes, int n_in,
                              void* d_out, int out_size, void* d_ws, size_t ws_size,
                              hipStream_t stream) {
  const float* x   = (const float*)d_in[0];
  const float* Wih = (const float*)d_in[1];
  const float* Whh = (const float*)d_in[2];
  const float* bih = (const float*)d_in[3];
  const float* bhh = (const float*)d_in[4];
  const float* fcw = (const float*)d_in[5];
  const float* fcb = (const float*)d_in[6];
  float* out = (float*)d_out;

  char* ws = (char*)d_ws;
  f16*      xh  = (f16*)ws;                                //  67,108,864 B
  f16*      Wh  = (f16*)(ws + 67108864);                   //   1,048,576 B
  f16*      xq  = (f16*)(ws + 68157440);                   // 134,217,728 B
  uint32_t* W8R = (uint32_t*)(ws + 202375168);             //     196,608 B
  uint32_t* W8O = (uint32_t*)(ws + 202571776);             //      65,536 B

  cvt_f16_kernel<<<16384, 256, 0, stream>>>(x,   xh, 33554432/8);
  cvt_f16_kernel<<<256,   256, 0, stream>>>(Wih, Wh, 524288/8);
  prep_whh8<<<256, 256, 0, stream>>>(Whh, W8R, W8O);
  gemm_xg_kernel<<<4096, 256, 0, stream>>>(xh, Wh, bih, bhh, xq);
  (void)hipFuncSetAttribute(reinterpret_cast<const void*>(lstm8_kernel),
                            hipFuncAttributeMaxDynamicSharedMemorySize, 67072);
  lstm8_kernel<<<BATCH, 256, 67072, stream>>>(xq, W8R, (const uint4*)W8O,
                                              fcw, fcb, out);
}